// Round 1
// 259.368 us; speedup vs baseline: 1.0673x; 1.0673x over previous
//
#include <hip/hip_runtime.h>

// Problem constants (from reference)
constexpr int B    = 1024;
constexpr int L    = 50;
constexpr int S    = 256;
constexpr int H    = 4;
constexpr int E    = 64;
constexpr int HID  = 64;
constexpr int SUPP = 10000;

// Branch-free tanh via exp2-based __expf; clamp keeps e finite (inputs here are
// O(1) anyway). Rel err ~1e-6, far under the absmax tolerance scale.
__device__ __forceinline__ float tanh_fast(float x) {
    const float xc = fminf(fmaxf(x, -15.0f), 15.0f);
    const float e  = __expf(2.0f * xc);
    return (e - 1.0f) * __builtin_amdgcn_rcpf(e + 1.0f);
}

// ---------------------------------------------------------------------------
// Kernel 1: fused pre-work.
//   blockIdx.y in {0,1}: user_fea_encode(call=y) + per-head q projection
//     (wave == head); fea never touches global memory.
//   blockIdx.y == 2:     K_supp[h][j][:] = tgt_user_emb[supp_users[j]] @ Wk[h]
// All 64-deep dot products use uniform-address float4 LDS reads (ds_read_b128
// broadcast, LGKM pipe) instead of v_readlane (VALU pipe), with 4 independent
// accumulators to break the dependency chain.
// Reference quirks preserved: src_item_emb for BOTH encode calls; encoder
// softmax has no max-subtract, padded rows contribute exp(0)=1; denom+1e-12.
// ---------------------------------------------------------------------------
__global__ __launch_bounds__(256) void pre_kernel(
    const int* __restrict__ x,            // (B,2)  [:,0]=user_id
    const int* __restrict__ src_his,      // (B,L)
    const int* __restrict__ src_hl,       // (B,)
    const int* __restrict__ tgt_his,      // (B,L)
    const int* __restrict__ tgt_hl,       // (B,)
    const float* __restrict__ item_emb,   // src_item_emb -- always src!
    const float* __restrict__ src_user_emb,
    const float* __restrict__ tgt_user_emb,
    const int* __restrict__ supp_users,   // (SUPP,)
    const float* __restrict__ W_att_w,    // (E,E)
    const float* __restrict__ W_att_b,    // (E,)
    const float* __restrict__ W_agg_w,    // (E,E)
    const float* __restrict__ Wq,         // (H,E,E)
    const float* __restrict__ Wk,         // (H,E,E)
    float* __restrict__ qout,             // (2,H,B,E)
    float* __restrict__ K_supp)           // (H,SUPP,E)
{
    const int tid  = threadIdx.x;
    const int lane = tid & 63;
    const int wave = tid >> 6;

    if (blockIdx.y == 2) {
        // ---------------- ksupp plane ----------------
        // 4 waves cooperatively stage 4 supp rows per iteration (each row
        // gathered ONCE), then wave h projects all 4 rows through Wk[h].
        __shared__ __align__(16) float sEv[4][E];
        const int h = wave;   // wave == head
        float wkc[E];
#pragma unroll
        for (int i = 0; i < E; i++) wkc[i] = Wk[h * E * E + i * E + lane];

        for (int j0 = blockIdx.x * 4; j0 < SUPP; j0 += gridDim.x * 4) {
            const int jm = j0 + wave;
            if (jm < SUPP) {
                const int u = supp_users[jm];
                sEv[wave][lane] = tgt_user_emb[(size_t)u * E + lane];
            }
            __syncthreads();
            const int mmax = min(4, SUPP - j0);
            for (int m = 0; m < mmax; m++) {
                const float4* e4 = (const float4*)&sEv[m][0];
                float a0 = 0.0f, a1 = 0.0f, a2 = 0.0f, a3 = 0.0f;
#pragma unroll
                for (int k = 0; k < 16; k++) {
                    const float4 v = e4[k];   // uniform addr -> LDS broadcast
                    a0 += v.x * wkc[4 * k + 0];
                    a1 += v.y * wkc[4 * k + 1];
                    a2 += v.z * wkc[4 * k + 2];
                    a3 += v.w * wkc[4 * k + 3];
                }
                K_supp[((size_t)h * SUPP + j0 + m) * E + lane] = (a0 + a1) + (a2 + a3);
            }
            __syncthreads();  // before sEv is overwritten
        }
        return;
    }

    // ---------------- encode + q plane ----------------
    __shared__ __align__(16) float sHist[L * E];
    __shared__ float sHs[L];
    __shared__ float sAtt[L];
    __shared__ float sPart[4][E];
    __shared__ __align__(16) float sOut[E];
    __shared__ __align__(16) float sFea[E];

    const int b    = blockIdx.x;
    const int call = blockIdx.y;

    const int* his = call ? tgt_his : src_his;
    const int* hl  = call ? tgt_hl  : src_hl;
    const float* user_table = call ? tgt_user_emb : src_user_emb;

    float wcol[E];
#pragma unroll
    for (int i = 0; i < E; i++) wcol[i] = W_att_w[i * E + lane];

    const int uid    = x[2 * b];
    const float uv   = user_table[(size_t)uid * E + lane];
    const float bias = W_att_b[lane];
    const int hlen   = hl[b];

    // phase 1a: gather + stage history rows; row sums for pad check
    for (int l = wave; l < L; l += 4) {
        const int it = his[b * L + l];
        const float hv = (l < hlen) ? item_emb[(size_t)it * E + lane] : 0.0f;
        sHist[l * E + lane] = hv;
        float hs = hv;
#pragma unroll
        for (int off = 32; off; off >>= 1) hs += __shfl_xor(hs, off);
        if (lane == 0) sHs[l] = hs;
    }
    __syncthreads();

    // phase 1b: key matmul + att logit per row (uniform float4 LDS broadcast)
    for (int l = wave; l < L; l += 4) {
        const float4* hrow = (const float4*)&sHist[l * E];
        float a0 = 0.0f, a1 = 0.0f, a2 = 0.0f, a3 = 0.0f;
#pragma unroll
        for (int k = 0; k < 16; k++) {
            const float4 h4 = hrow[k];
            a0 += h4.x * wcol[4 * k + 0];
            a1 += h4.y * wcol[4 * k + 1];
            a2 += h4.z * wcol[4 * k + 2];
            a3 += h4.w * wcol[4 * k + 3];
        }
        float part = tanh_fast((a0 + a1) + (a2 + a3) + bias) * uv;
#pragma unroll
        for (int off = 32; off; off >>= 1) part += __shfl_xor(part, off);
        const float hs = sHs[l];
        if (lane == 0) sAtt[l] = (hs == 0.0f) ? 0.0f : part;
    }
    __syncthreads();

    // softmax (no max-subtract; padded rows contribute exp(0)=1)
    if (wave == 0) {
        float v = (lane < L) ? __expf(sAtt[lane]) : 0.0f;
        float s = v;
#pragma unroll
        for (int off = 32; off; off >>= 1) s += __shfl_xor(s, off);
        const float denom = s + 1e-12f;
        if (lane < L) sAtt[lane] = v / denom;
    }
    __syncthreads();

    // ctx partials across waves
    float c = 0.0f;
    for (int l = wave; l < L; l += 4) c += sAtt[l] * sHist[l * E + lane];
    sPart[wave][lane] = c;
    __syncthreads();
    if (tid < E) sOut[tid] = sPart[0][tid] + sPart[1][tid] + sPart[2][tid] + sPart[3][tid];
    __syncthreads();

    // agg: fea = ctx @ W_agg, i-range split across waves
    {
        const float4* o4 = (const float4*)&sOut[wave * 16];
        float g0 = 0.0f, g1 = 0.0f, g2 = 0.0f, g3 = 0.0f;
#pragma unroll
        for (int k = 0; k < 4; k++) {
            const float4 v = o4[k];
            const int i = wave * 16 + 4 * k;
            g0 += v.x * W_agg_w[(i + 0) * E + lane];
            g1 += v.y * W_agg_w[(i + 1) * E + lane];
            g2 += v.z * W_agg_w[(i + 2) * E + lane];
            g3 += v.w * W_agg_w[(i + 3) * E + lane];
        }
        sPart[wave][lane] = (g0 + g1) + (g2 + g3);
    }
    __syncthreads();
    if (tid < E) sFea[tid] = sPart[0][tid] + sPart[1][tid] + sPart[2][tid] + sPart[3][tid];
    __syncthreads();

    // q projection, wave == head (uniform float4 LDS broadcast of fea)
    {
        const float* Wqh = Wq + wave * E * E;
        const float4* f4p = (const float4*)sFea;
        float q0 = 0.0f, q1 = 0.0f, q2 = 0.0f, q3 = 0.0f;
#pragma unroll
        for (int k = 0; k < 16; k++) {
            const float4 f4 = f4p[k];
            q0 += f4.x * Wqh[(4 * k + 0) * E + lane];
            q1 += f4.y * Wqh[(4 * k + 1) * E + lane];
            q2 += f4.z * Wqh[(4 * k + 2) * E + lane];
            q3 += f4.w * Wqh[(4 * k + 3) * E + lane];
        }
        qout[(((call * H) + wave) * B + b) * E + lane] = (q0 + q1) + (q2 + q3);
    }
}

// ---------------------------------------------------------------------------
// Kernel 2: attention per (b,h,call).  K tile lives in REGISTERS:
// lane = (rsub = lane>>4, u = lane&15); wave w owns rows [w*64,(w+1)*64);
// kreg[i] = row (s0+4i+rsub), unit u (4 floats).  Logits via in-lane partial
// dot + 4-step shuffle reduce in 16-lane subgroups.  softmax = jax.nn.softmax
// (max-subtracted).  ctx is pure-VALU FMA over the register tile (p via
// shfl).  ctx uses k itself (reference quirk); g = ctx @ Wv[h].
//
// XCD pinning: grid is flattened to 8192 blocks; (h,call) = blockIdx & 7 so
// that (assuming round-robin block->XCD dispatch) every consumer of head h's
// 2.56 MB K table lands on the same XCD and gathers hit that XCD's 4 MB L2
// instead of Infinity Cache.  Perf heuristic only — correctness unaffected.
// ---------------------------------------------------------------------------
__global__ __launch_bounds__(256) void attn_kernel(
    const int* __restrict__ sample_idx,  // (2,H,B,S)
    const float* __restrict__ K_supp,    // (H,SUPP,E)
    const float* __restrict__ qarr,      // (2,H,B,E)
    const float* __restrict__ Wv,        // (H,E,E)
    float* __restrict__ gout)            // (2,B,H*E)
{
    __shared__ float sRed[8];
    __shared__ float sCtx[4][E];
    __shared__ float sC[E];
    __shared__ float sG[4][E];

    const int n    = blockIdx.x;
    const int xcd  = n & 7;
    const int h    = xcd >> 1;
    const int call = xcd & 1;
    const int b    = n >> 3;
    const int tid  = threadIdx.x;
    const int lane = tid & 63;
    const int wave = tid >> 6;
    const int u    = lane & 15;
    const int rsub = lane >> 4;
    const int s0   = wave * 64;

    const int* idx = sample_idx + (((call * H) + h) * B + b) * S;
    const float* Kh = K_supp + (size_t)h * SUPP * E;
    const float4 qu = *(const float4*)(qarr + ((size_t)(((call * H) + h) * B + b)) * E + 4 * u);

    // ---- gather into registers + logits ----
    float4 kreg[16];
    float mylogit = 0.0f;
#pragma unroll
    for (int i = 0; i < 16; i++) {
        const int j = idx[s0 + 4 * i + rsub];
        kreg[i] = *(const float4*)(Kh + (size_t)j * E + 4 * u);
        float part = kreg[i].x * qu.x + kreg[i].y * qu.y
                   + kreg[i].z * qu.z + kreg[i].w * qu.w;
#pragma unroll
        for (int off = 1; off < 16; off <<= 1) part += __shfl_xor(part, off);
        mylogit = (u == i) ? part : mylogit;   // lane holds row s0 + 4u + rsub
    }

    // ---- block softmax over 256 logits (permutation-invariant) ----
    float m = mylogit;
#pragma unroll
    for (int off = 32; off; off >>= 1) m = fmaxf(m, __shfl_xor(m, off));
    if (lane == 0) sRed[wave] = m;
    __syncthreads();
    const float mx = fmaxf(fmaxf(sRed[0], sRed[1]), fmaxf(sRed[2], sRed[3]));
    const float ex = __expf(mylogit - mx);
    float sm = ex;
#pragma unroll
    for (int off = 32; off; off >>= 1) sm += __shfl_xor(sm, off);
    if (lane == 0) sRed[4 + wave] = sm;
    __syncthreads();
    const float denom = sRed[4] + sRed[5] + sRed[6] + sRed[7];
    const float pval = ex / denom;   // weight of row s0 + 4u + rsub

    // ---- ctx: pure-VALU FMA over register tile ----
    // row s0+4i+rsub's weight lives at lane 16*rsub + i
    float4 cacc = make_float4(0.0f, 0.0f, 0.0f, 0.0f);
#pragma unroll
    for (int i = 0; i < 16; i++) {
        const float p = __shfl(pval, (lane & 48) + i);
        cacc.x += p * kreg[i].x;
        cacc.y += p * kreg[i].y;
        cacc.z += p * kreg[i].z;
        cacc.w += p * kreg[i].w;
    }
    // combine across rsub groups (lanes l, l^16, l^32, l^48 share unit u)
#pragma unroll
    for (int off = 16; off <= 32; off <<= 1) {
        cacc.x += __shfl_xor(cacc.x, off);
        cacc.y += __shfl_xor(cacc.y, off);
        cacc.z += __shfl_xor(cacc.z, off);
        cacc.w += __shfl_xor(cacc.w, off);
    }
    if (lane < 16) *(float4*)(&sCtx[wave][u * 4]) = cacc;
    __syncthreads();
    if (wave == 0) {
        sC[lane] = sCtx[0][lane] + sCtx[1][lane] + sCtx[2][lane] + sCtx[3][lane];
    }
    __syncthreads();

    // ---- g = ctx @ Wv[h], c-range split across waves ----
    const float* Wvh = Wv + h * E * E;
    float g = 0.0f;
#pragma unroll
    for (int k = 0; k < 16; k++) {
        const int c = wave * 16 + k;
        g += sC[c] * Wvh[c * E + lane];
    }
    sG[wave][lane] = g;
    __syncthreads();
    if (wave == 0) {
        gout[((size_t)(call * B) + b) * (H * E) + h * E + lane] =
            sG[0][lane] + sG[1][lane] + sG[2][lane] + sG[3][lane];
    }
}

// ---------------------------------------------------------------------------
// Kernel 3: W_out projection + final MLP + all four outputs.
// out layout: [output(B) | x3(B) | out_emb_s(B*E) | x2(B*E)]
// ---------------------------------------------------------------------------
__global__ __launch_bounds__(256) void final_kernel(
    const int* __restrict__ x,             // (B,2) [:,1]=item_id
    const float* __restrict__ tgt_item_emb,
    const float* __restrict__ gsrc,        // (B, H*E) -> user_emb path
    const float* __restrict__ gtgt,        // (B, H*E) -> hybrid path
    const float* __restrict__ W_out,       // (H*E, E)
    const float* __restrict__ l1_w,        // (2E, HID)
    const float* __restrict__ l1_b,        // (HID,)
    const float* __restrict__ l2_w,        // (HID, E)
    const float* __restrict__ l2_b,        // (E,)
    const float* __restrict__ l3_w,        // (E,1)
    const float* __restrict__ l3_b,        // (1,)
    float* __restrict__ out)
{
    __shared__ float sPart[4][E];
    __shared__ float sHyb[E];
    __shared__ float sItem[E];
    __shared__ float sX1[HID];

    const int b    = blockIdx.x;
    const int tid  = threadIdx.x;
    const int lane = tid & 63;
    const int wave = tid >> 6;

    if (tid < E) {
        const int item = x[2 * b + 1];
        sItem[tid] = tgt_item_emb[(size_t)item * E + tid];
    }

    const float* grow = (wave < 2) ? (gsrc + (size_t)b * (H * E))
                                   : (gtgt + (size_t)b * (H * E));
    const int i0 = (wave & 1) * 128;
    {
        const float4* g4 = (const float4*)(grow + i0);
        float a0 = 0.0f, a1 = 0.0f, a2 = 0.0f, a3 = 0.0f;
#pragma unroll
        for (int k = 0; k < 32; k++) {
            const float4 v = g4[k];
            const float* wr = W_out + (i0 + 4 * k) * E + lane;
            a0 += v.x * wr[0];
            a1 += v.y * wr[E];
            a2 += v.z * wr[2 * E];
            a3 += v.w * wr[3 * E];
        }
        sPart[wave][lane] = (a0 + a1) + (a2 + a3);
    }
    __syncthreads();

    if (wave == 0) {
        const float ue = sPart[0][lane] + sPart[1][lane];
        const float prod = ue * sItem[lane];
        out[2 * B + b * E + lane] = prod;  // out_emb_s
        float s = prod;
#pragma unroll
        for (int off = 32; off; off >>= 1) s += __shfl_xor(s, off);
        if (lane == 0) out[b] = s;         // output
    }
    if (wave == 1) {
        sHyb[lane] = sPart[2][lane] + sPart[3][lane];
    }
    __syncthreads();

    // l1: 128-deep sum split across 4 waves (waves 0,1: hybrid; 2,3: item)
    float a1 = 0.0f;
#pragma unroll
    for (int k = 0; k < 32; k++) {
        const int i = wave * 32 + k;
        const float v = (i < 64) ? sHyb[i] : sItem[i - 64];
        a1 += v * l1_w[i * HID + lane];
    }
    sPart[wave][lane] = a1;
    __syncthreads();

    if (wave == 0) {
        const float a = l1_b[lane] + sPart[0][lane] + sPart[1][lane]
                      + sPart[2][lane] + sPart[3][lane];
        sX1[lane] = tanh_fast(a);
    }
    __syncthreads();

    if (wave == 0) {
        float a = l2_b[lane];
#pragma unroll
        for (int i = 0; i < HID; i++) a += sX1[i] * l2_w[i * E + lane];
        const float x2 = tanh_fast(a);
        out[2 * B + B * E + b * E + lane] = x2;  // x2_t
        float p = x2 * l3_w[lane];
#pragma unroll
        for (int off = 32; off; off >>= 1) p += __shfl_xor(p, off);
        if (lane == 0) out[B + b] = p + l3_b[0]; // x3_t
    }
}

// ---------------------------------------------------------------------------
extern "C" void kernel_launch(void* const* d_in, const int* in_sizes, int n_in,
                              void* d_out, int out_size, void* d_ws, size_t ws_size,
                              hipStream_t stream) {
    const int*   x            = (const int*)d_in[0];
    const int*   src_his      = (const int*)d_in[1];
    const int*   src_hl       = (const int*)d_in[2];
    const int*   tgt_his      = (const int*)d_in[3];
    const int*   tgt_hl       = (const int*)d_in[4];
    const int*   sample_idx   = (const int*)d_in[5];
    const int*   supp_users   = (const int*)d_in[6];
    const float* src_user_emb = (const float*)d_in[7];
    const float* src_item_emb = (const float*)d_in[8];
    const float* tgt_user_emb = (const float*)d_in[9];
    const float* tgt_item_emb = (const float*)d_in[10];
    const float* W_att_w      = (const float*)d_in[11];
    const float* W_att_b      = (const float*)d_in[12];
    const float* W_agg_w      = (const float*)d_in[13];
    const float* Wq           = (const float*)d_in[14];
    const float* Wk           = (const float*)d_in[15];
    const float* Wv           = (const float*)d_in[16];
    const float* W_out        = (const float*)d_in[17];
    const float* l1_w         = (const float*)d_in[18];
    const float* l1_b         = (const float*)d_in[19];
    const float* l2_w         = (const float*)d_in[20];
    const float* l2_b         = (const float*)d_in[21];
    const float* l3_w         = (const float*)d_in[22];
    const float* l3_b         = (const float*)d_in[23];

    float* ws      = (float*)d_ws;
    float* qarr    = ws;                                  // 2*H*B*E
    float* K_supp  = qarr + 2 * H * B * E;                // H*SUPP*E
    float* garr    = K_supp + H * SUPP * E;               // 2*B*H*E
    float* out     = (float*)d_out;

    pre_kernel<<<dim3(B, 3), 256, 0, stream>>>(
        x, src_his, src_hl, tgt_his, tgt_hl, src_item_emb,
        src_user_emb, tgt_user_emb, supp_users,
        W_att_w, W_att_b, W_agg_w, Wq, Wk, qarr, K_supp);
    attn_kernel<<<dim3(B * H * 2), 256, 0, stream>>>(
        sample_idx, K_supp, qarr, Wv, garr);
    final_kernel<<<dim3(B), 256, 0, stream>>>(
        x, tgt_item_emb, garr, garr + B * H * E, W_out,
        l1_w, l1_b, l2_w, l2_b, l3_w, l3_b, out);
}